// Round 15
// baseline (238.571 us; speedup 1.0000x reference)
//
#include <hip/hip_runtime.h>
#include <hip/hip_bf16.h>

typedef short bf16x8 __attribute__((ext_vector_type(8)));
typedef short bf16x4 __attribute__((ext_vector_type(4)));
typedef float f32x4 __attribute__((ext_vector_type(4)));
typedef unsigned uint2v __attribute__((ext_vector_type(2)));

#define MFMA16(a, b, c) __builtin_amdgcn_mfma_f32_16x16x32_bf16((a), (b), (c), 0, 0, 0)

#if __has_builtin(__builtin_amdgcn_mfma_f32_16x16x16_bf16)
#define MFMAK16(a, b, c) __builtin_amdgcn_mfma_f32_16x16x16_bf16((a), (b), (c), 0, 0, 0)
#else
#define MFMAK16(a, b, c) __builtin_amdgcn_mfma_f32_16x16x16bf16_1k((a), (b), (c), 0, 0, 0)
#endif

#if __has_builtin(__builtin_amdgcn_exp2f)
#define EXP2(x) __builtin_amdgcn_exp2f(x)
#else
#define EXP2(x) exp2f(x)
#endif

static constexpr int B_ = 2, S_ = 2048, D_ = 1024, H_ = 16, DH = 64;
static constexpr int M_ = B_ * S_;   // 4096
static constexpr int K_ = D_;        // 1024
static constexpr float kQS = 0.18033688011112042f;   // log2(e)/8, folded into Wq

static __device__ __forceinline__ ushort f2bf(float f) {
    __hip_bfloat16 h = __float2bfloat16(f);
    return *reinterpret_cast<ushort*>(&h);
}

static __device__ __forceinline__ void gload16(const ushort* g, ushort* l) {
    __builtin_amdgcn_global_load_lds((const __attribute__((address_space(1))) void*)g,
                                     (__attribute__((address_space(3))) void*)l, 16, 0, 0);
}

// pack two fp32 -> (bf16(hi) << 16) | bf16(lo), truncation (v_perm_b32)
static __device__ __forceinline__ unsigned pkbf(float lo, float hi) {
    return __builtin_amdgcn_perm(__builtin_bit_cast(unsigned, hi),
                                 __builtin_bit_cast(unsigned, lo), 0x07060302u);
}

// ---------------------------------------------------------------------------
// Prep: z=0..3 -> fused convert+transpose of the 4 weights (Wq pre-scaled by
// log2(e)/8); z=4 -> fp32->bf16 convert of x.
// ---------------------------------------------------------------------------
__global__ __launch_bounds__(256) void prep5(const float* __restrict__ x,
                                             const float* __restrict__ W0,
                                             const float* __restrict__ W1,
                                             const float* __restrict__ W2,
                                             const float* __restrict__ W3,
                                             ushort* __restrict__ xb,
                                             ushort* __restrict__ T0,
                                             ushort* __restrict__ T1,
                                             ushort* __restrict__ T2,
                                             ushort* __restrict__ T3) {
    int z = blockIdx.z;
    int tx = threadIdx.x, ty = threadIdx.y;
    int t = ty * 32 + tx;
    if (z == 4) {
        int blk = blockIdx.y * 32 + blockIdx.x;
#pragma unroll
        for (int k = 0; k < 4; k++) {
            int i = blk * 1024 + k * 256 + t;
            float4 v = reinterpret_cast<const float4*>(x)[i];
            ushort4 o;
            o.x = f2bf(v.x); o.y = f2bf(v.y); o.z = f2bf(v.z); o.w = f2bf(v.w);
            reinterpret_cast<ushort4*>(xb)[i] = o;
        }
        return;
    }
    __shared__ float tile[32][33];
    const float* W = (z == 0) ? W0 : (z == 1) ? W1 : (z == 2) ? W2 : W3;
    ushort* T = (z == 0) ? T0 : (z == 1) ? T1 : (z == 2) ? T2 : T3;
    float sc = (z == 0) ? kQS : 1.0f;
    int bx = blockIdx.x, by = blockIdx.y;
#pragma unroll
    for (int i = 0; i < 4; i++)
        tile[ty + i * 8][tx] = W[(by * 32 + ty + i * 8) * D_ + bx * 32 + tx];
    __syncthreads();
#pragma unroll
    for (int i = 0; i < 4; i++)
        T[(bx * 32 + ty + i * 8) * K_ + by * 32 + tx] = f2bf(tile[tx][ty + i * 8] * sc);
}

// ---------------------------------------------------------------------------
// m97-style GEMM (single-buffered), swapped-operand vector epilogues (r13).
// MODE 0 (TN=128): fused QKV; MODE 1 (TN=64): O-proj fp32 + bias.
// ---------------------------------------------------------------------------
template <int MODE, int TN>
__global__ __launch_bounds__(256, 3) void gemm128(const ushort* __restrict__ A,
                                                  const ushort* __restrict__ Wt,
                                                  const float* __restrict__ bias_q,
                                                  const float* __restrict__ bias_k,
                                                  const float* __restrict__ bias_v,
                                                  ushort* __restrict__ Qb,
                                                  ushort* __restrict__ Kb,
                                                  ushort* __restrict__ Vtb,
                                                  float* __restrict__ outf) {
    constexpr int NJ = TN / 32;
    __shared__ __align__(16) ushort As[128 * 32];
    __shared__ __align__(16) ushort Bs[TN * 32];

    int m0 = blockIdx.x * 128;
    int n0 = blockIdx.y * TN;
    int t = threadIdx.x;
    int lane = t & 63, w = t >> 6;
    int ln = lane & 15, lq = lane >> 4;
    int wm = (w >> 1) * 64, wn = (w & 1) * (TN / 2);

    int c0 = t, c1 = t + 256;
    const ushort* Ag0 = A + (size_t)(m0 + (c0 >> 2)) * K_ + (c0 & 3) * 8;
    const ushort* Ag1 = A + (size_t)(m0 + (c1 >> 2)) * K_ + (c1 & 3) * 8;
    const ushort* Bg0 = Wt + (size_t)(n0 + (c0 >> 2)) * K_ + (c0 & 3) * 8;
    const ushort* Bg1 = Wt + (size_t)(n0 + (c1 >> 2)) * K_ + (c1 & 3) * 8;
    ushort* Al0 = As + c0 * 8;
    ushort* Al1 = As + c1 * 8;
    ushort* Bl0 = Bs + c0 * 8;
    ushort* Bl1 = Bs + c1 * 8;

    const bool swp = (MODE == 1) || (n0 < 2048);   // block-uniform

    f32x4 acc[4][NJ];
#pragma unroll
    for (int i = 0; i < 4; i++)
#pragma unroll
        for (int j = 0; j < NJ; j++) acc[i][j] = f32x4{0.f, 0.f, 0.f, 0.f};

    if (swp) {
        for (int k0 = 0; k0 < K_; k0 += 32) {
            gload16(Ag0 + k0, Al0);
            gload16(Ag1 + k0, Al1);
            gload16(Bg0 + k0, Bl0);
            if (TN == 128) gload16(Bg1 + k0, Bl1);
            __syncthreads();
            bf16x8 af[4], bfr[NJ];
#pragma unroll
            for (int i = 0; i < 4; i++)
                af[i] = *reinterpret_cast<const bf16x8*>(As + (wm + i * 16 + ln) * 32 + lq * 8);
#pragma unroll
            for (int j = 0; j < NJ; j++)
                bfr[j] = *reinterpret_cast<const bf16x8*>(Bs + (wn + j * 16 + ln) * 32 + lq * 8);
#pragma unroll
            for (int i = 0; i < 4; i++)
#pragma unroll
                for (int j = 0; j < NJ; j++)
                    acc[i][j] = MFMA16(bfr[j], af[i], acc[i][j]);   // swapped
            __syncthreads();
        }
    } else {
        for (int k0 = 0; k0 < K_; k0 += 32) {
            gload16(Ag0 + k0, Al0);
            gload16(Ag1 + k0, Al1);
            gload16(Bg0 + k0, Bl0);
            if (TN == 128) gload16(Bg1 + k0, Bl1);
            __syncthreads();
            bf16x8 af[4], bfr[NJ];
#pragma unroll
            for (int i = 0; i < 4; i++)
                af[i] = *reinterpret_cast<const bf16x8*>(As + (wm + i * 16 + ln) * 32 + lq * 8);
#pragma unroll
            for (int j = 0; j < NJ; j++)
                bfr[j] = *reinterpret_cast<const bf16x8*>(Bs + (wn + j * 16 + ln) * 32 + lq * 8);
#pragma unroll
            for (int i = 0; i < 4; i++)
#pragma unroll
                for (int j = 0; j < NJ; j++)
                    acc[i][j] = MFMA16(af[i], bfr[j], acc[i][j]);
            __syncthreads();
        }
    }

    if (MODE == 1) {
#pragma unroll
        for (int j = 0; j < NJ; j++) {
            int nb = n0 + wn + j * 16 + lq * 4;
            float4 bv4 = *reinterpret_cast<const float4*>(bias_q + nb);
#pragma unroll
            for (int i = 0; i < 4; i++) {
                int m = m0 + wm + i * 16 + ln;
                float4 o;
                o.x = acc[i][j][0] + bv4.x;
                o.y = acc[i][j][1] + bv4.y;
                o.z = acc[i][j][2] + bv4.z;
                o.w = acc[i][j][3] + bv4.w;
                *reinterpret_cast<float4*>(outf + (size_t)m * D_ + nb) = o;
            }
        }
    } else if (n0 < 2048) {
        int which = n0 >> 10;
        const float* bp = which ? bias_k : bias_q;
        ushort* dst = which ? Kb : Qb;
        float bsc = which ? 1.0f : kQS;
#pragma unroll
        for (int j = 0; j < NJ; j++) {
            int nb = ((n0 + wn + j * 16) & 1023) + lq * 4;
            int h = nb >> 6, dhb = nb & 63;
            float4 bv4 = *reinterpret_cast<const float4*>(bp + nb);
            bv4.x *= bsc; bv4.y *= bsc; bv4.z *= bsc; bv4.w *= bsc;
#pragma unroll
            for (int i = 0; i < 4; i++) {
                int m = m0 + wm + i * 16 + ln;
                int b = m >> 11, s = m & 2047;
                ushort4 o4;
                o4.x = f2bf(acc[i][j][0] + bv4.x);
                o4.y = f2bf(acc[i][j][1] + bv4.y);
                o4.z = f2bf(acc[i][j][2] + bv4.z);
                o4.w = f2bf(acc[i][j][3] + bv4.w);
                *reinterpret_cast<ushort4*>(dst + (((size_t)(b * H_ + h) * S_) + s) * DH + dhb) = o4;
            }
        }
    } else {
#pragma unroll
        for (int j = 0; j < NJ; j++) {
            int n = n0 + wn + j * 16 + ln;
            int nn = n & 1023, h = nn >> 6, dh = nn & 63;
            float bv = bias_v[nn];
#pragma unroll
            for (int i = 0; i < 4; i++) {
                int m = m0 + wm + i * 16 + lq * 4;
                int b = m >> 11, s0 = m & 2047;
                ushort4 o4;
                o4.x = f2bf(acc[i][j][0] + bv);
                o4.y = f2bf(acc[i][j][1] + bv);
                o4.z = f2bf(acc[i][j][2] + bv);
                o4.w = f2bf(acc[i][j][3] + bv);
                *reinterpret_cast<ushort4*>(Vtb + (((size_t)(b * H_ + h) * DH) + dh) * S_ + s0) = o4;
            }
        }
    }
}

// ---------------------------------------------------------------------------
// Flash attention v9 "wave-per-key-slice": block = 64 q-rows of one (b,h),
// grid = 1024. Each wave owns a 16-KEY slice of the 64-key tile and computes
// all 4 q-tiles -> P NEVER touches LDS:
//  - S^T = K·Q^T (swapped): D gives lane q=ln, keys lq*4+r — which IS the
//    B-operand layout of mfma_f32_16x16x16_bf16 (B[k=lq*4+j][n=ln]).
//    exp + 2 v_perm packs -> PV B-frag in registers.
//  - PV via O^T = V^T·P: A = V^T[dh][key] b64 from the r14 Vl layout
//    (2-way bank phase, free); D = O^T accumulated per (dh-tile, q-tile).
//  - K staging/layout identical to r14 (kf = b128, 2-way phase).
// Per wave-iter LDS ~48 cyc for 64 q-rows (r14: 304 per 128) — ~3x lighter.
// No K-split: no combine kernel, no partial traffic. Epilogue: cross-wave
// O reduction via LDS (reuses KV space), one nt-round at a time; l reduced
// by shuffles + 1 KB LDS. VGPR ~140 (o_acc 64 + qf 32) -> ~12 waves/CU.
// ---------------------------------------------------------------------------
__global__ __launch_bounds__(256) void attn_ks(const ushort* __restrict__ Q,
                                               const ushort* __restrict__ K,
                                               const ushort* __restrict__ Vt,
                                               ushort* __restrict__ O) {
    __shared__ __align__(16) ushort SM[8192 + 512];   // 16 KB KV / Ored + 1 KB lw
    ushort* Kl = SM;                      // 8 KB: [kg 0..7][key 0..63] chunks
    ushort* Vl = SM + 4096;               // 8 KB: [kg 0..7][dh 0..63] chunks
    float* Ored = (float*)SM;             // 16 KB, epilogue (aliases Kl/Vl)
    float* lw = (float*)(SM + 8192);      // 256 f32

    int bid = blockIdx.x;
    int qb = bid & 31;         // 32 q-blocks of 64 rows
    int bh = bid >> 5;         // b*H + h
    int t = threadIdx.x;
    int lane = t & 63, w = t >> 6;
    int ln = lane & 15, lq = lane >> 4;
    int q0 = qb * 64;

    const ushort* Qp = Q + (size_t)bh * S_ * DH;
    const ushort* Kp = K + (size_t)bh * S_ * DH;
    const ushort* Vp = Vt + (size_t)bh * DH * S_;

    // Q B-frags for all 4 q-tiles (B[k=lq*8+j][n=ln])
    bf16x8 qf[4][2];
#pragma unroll
    for (int qt = 0; qt < 4; qt++) {
        const ushort* qp = Qp + (q0 + qt * 16 + ln) * DH + lq * 8;
        qf[qt][0] = *reinterpret_cast<const bf16x8*>(qp);
        qf[qt][1] = *reinterpret_cast<const bf16x8*>(qp + 32);
    }

    // staging (identical to r14): chunk c <-> (key/dh = c&63, kgroup = c>>6)
    int c0 = t, c1 = t + 256;
    const ushort* Kg0 = Kp + (size_t)(c0 & 63) * DH + (c0 >> 6) * 8;
    const ushort* Kg1 = Kp + (size_t)(c1 & 63) * DH + (c1 >> 6) * 8;
    const ushort* Vg0 = Vp + (size_t)(c0 & 63) * S_ + (c0 >> 6) * 8;
    const ushort* Vg1 = Vp + (size_t)(c1 & 63) * S_ + (c1 >> 6) * 8;
    ushort* Kl0 = Kl + c0 * 8;
    ushort* Kl1 = Kl + c1 * 8;
    ushort* Vl0 = Vl + c0 * 8;
    ushort* Vl1 = Vl + c1 * 8;

    f32x4 o_acc[4][4];         // [dh-tile nt][q-tile qt], O^T layout
    float l_part[4] = {0.f, 0.f, 0.f, 0.f};
#pragma unroll
    for (int nt = 0; nt < 4; nt++)
#pragma unroll
        for (int qt = 0; qt < 4; qt++) o_acc[nt][qt] = f32x4{0.f, 0.f, 0.f, 0.f};

    for (int kt = 0; kt < S_ / 64; kt++) {
        int kb = kt * 64;
        gload16(Kg0 + (size_t)kb * DH, Kl0);
        gload16(Kg1 + (size_t)kb * DH, Kl1);
        gload16(Vg0 + kb, Vl0);
        gload16(Vg1 + kb, Vl1);
        __syncthreads();           // sync_a: tile staged

        // K A-frags for THIS WAVE's key slice (key = w*16 + ln)
        bf16x8 kf0 = *reinterpret_cast<const bf16x8*>(Kl + (lq * 64 + w * 16 + ln) * 8);
        bf16x8 kf1 = *reinterpret_cast<const bf16x8*>(Kl + ((4 + lq) * 64 + w * 16 + ln) * 8);

        // S^T + exp + in-register P pack (PV B-frags)
        bf16x4 pfr[4];
#pragma unroll
        for (int qt = 0; qt < 4; qt++) {
            f32x4 c = {0.f, 0.f, 0.f, 0.f};
            c = MFMA16(kf0, qf[qt][0], c);
            c = MFMA16(kf1, qf[qt][1], c);
            float p0 = EXP2(c[0]);
            float p1 = EXP2(c[1]);
            float p2 = EXP2(c[2]);
            float p3 = EXP2(c[3]);
            l_part[qt] += (p0 + p1) + (p2 + p3);
            uint2v pk;
            pk.x = pkbf(p0, p1);
            pk.y = pkbf(p2, p3);
            pfr[qt] = __builtin_bit_cast(bf16x4, pk);
        }
        // PV: O^T[dh][q] += V^T · P, K=16 (this wave's keys)
#pragma unroll
        for (int nt = 0; nt < 4; nt++) {
            bf16x4 vf = *reinterpret_cast<const bf16x4*>(
                Vl + ((w * 2 + (lq >> 1)) * 64 + nt * 16 + ln) * 8 + (lq & 1) * 4);
#pragma unroll
            for (int qt = 0; qt < 4; qt++)
                o_acc[nt][qt] = MFMAK16(vf, pfr[qt], o_acc[nt][qt]);
        }
        __syncthreads();           // sync_b: KV reads done; next gloads safe
    }

    // ---- l: reduce over the 4 lq-lanes, publish per-wave sums ----
#pragma unroll
    for (int qt = 0; qt < 4; qt++) {
        l_part[qt] += __shfl_xor(l_part[qt], 16, 64);
        l_part[qt] += __shfl_xor(l_part[qt], 32, 64);
    }
    if (lq == 0) {
#pragma unroll
        for (int qt = 0; qt < 4; qt++) lw[(w * 4 + qt) * 16 + ln] = l_part[qt];
    }

    // ---- cross-wave O reduction, one dh-tile (nt) per round ----
    int b = bh >> 4, h = bh & 15;
    float linv = 0.f;
#pragma unroll
    for (int nt = 0; nt < 4; nt++) {
        __syncthreads();           // prev round's reads done (+ lw visible)
#pragma unroll
        for (int qt = 0; qt < 4; qt++)
            *reinterpret_cast<f32x4*>(Ored + w * 1024 + qt * 256 + lane * 4) = o_acc[nt][qt];
        __syncthreads();
        // wave w owns q-tile qt=w: sum the 4 waves' partials
        f32x4 s = {0.f, 0.f, 0.f, 0.f};
#pragma unroll
        for (int wv = 0; wv < 4; wv++) {
            f32x4 p = *reinterpret_cast<const f32x4*>(Ored + wv * 1024 + w * 256 + lane * 4);
            s[0] += p[0]; s[1] += p[1]; s[2] += p[2]; s[3] += p[3];
        }
        if (nt == 0) {
            float L = lw[(0 * 4 + w) * 16 + ln] + lw[(1 * 4 + w) * 16 + ln] +
                      lw[(2 * 4 + w) * 16 + ln] + lw[(3 * 4 + w) * 16 + ln];
            linv = 1.0f / L;
        }
        // lane holds q = q0 + w*16 + ln, dh = nt*16 + lq*4 + r
        ushort4 o4;
        o4.x = f2bf(s[0] * linv);
        o4.y = f2bf(s[1] * linv);
        o4.z = f2bf(s[2] * linv);
        o4.w = f2bf(s[3] * linv);
        int sq = q0 + w * 16 + ln;
        *reinterpret_cast<ushort4*>(O + ((size_t)(b * S_ + sq) * H_ + h) * DH + nt * 16 + lq * 4) = o4;
    }
}

// ---------------------------------------------------------------------------
extern "C" void kernel_launch(void* const* d_in, const int* in_sizes, int n_in,
                              void* d_out, int out_size, void* d_ws, size_t ws_size,
                              hipStream_t stream) {
    const float* x  = (const float*)d_in[0];
    const float* Wq = (const float*)d_in[1];
    const float* bq = (const float*)d_in[2];
    const float* Wk = (const float*)d_in[3];
    const float* bk = (const float*)d_in[4];
    const float* Wv = (const float*)d_in[5];
    const float* bv = (const float*)d_in[6];
    const float* Wo = (const float*)d_in[7];
    const float* bo = (const float*)d_in[8];
    float* out = (float*)d_out;

    char* ws = (char*)d_ws;
    const size_t MB = 1024 * 1024;
    ushort* wtq = (ushort*)(ws + 0 * MB);    // [3072,1024] fused q,k,v contiguous
    ushort* wtk = (ushort*)(ws + 2 * MB);
    ushort* wtv = (ushort*)(ws + 4 * MB);
    ushort* wto = (ushort*)(ws + 6 * MB);
    ushort* xb  = (ushort*)(ws + 8 * MB);    // bf16 x [M,K]
    ushort* Qb  = (ushort*)(ws + 16 * MB);   // [B,H,S,Dh] (pre-scaled by kQS)
    ushort* Kb  = (ushort*)(ws + 24 * MB);   // [B,H,S,Dh]
    ushort* Vtb = (ushort*)(ws + 32 * MB);   // [B,H,Dh,S]
    ushort* AO  = (ushort*)(ws + 40 * MB);   // [B,S,D] bf16

    // prep: 4 weight transposes (z=0..3) + x convert (z=4)
    prep5<<<dim3(32, 32, 5), dim3(32, 8), 0, stream>>>(
        x, Wq, Wk, Wv, Wo, xb, wtq, wtk, wtv, wto);

    // fused QKV projection: N = 3072, 128x128 tiles -> 768 blocks = 3/CU
    gemm128<0, 128><<<dim3(M_ / 128, 3072 / 128), 256, 0, stream>>>(
        xb, wtq, bq, bk, bv, Qb, Kb, Vtb, nullptr);

    // attention: wave-per-key-slice, P in registers; 1024 blocks
    attn_ks<<<32 * 32, 256, 0, stream>>>(Qb, Kb, Vtb, AO);

    // output projection: N = 1024, 128x64 tiles -> 512 blocks = 2/CU
    gemm128<1, 64><<<dim3(M_ / 128, D_ / 64), 256, 0, stream>>>(
        AO, wto, bo, nullptr, nullptr, nullptr, nullptr, nullptr, out);
}